// Round 4
// baseline (28.812 us; speedup 1.0000x reference)
//
#include <hip/hip_runtime.h>
#include <math.h>

#define TLEN 4096
#define LEVELS 4
#define CHANS 32
#define SLOPE 10.0f

typedef float vfloat4 __attribute__((ext_vector_type(4)));

__device__ __forceinline__ float clamp30(float v) {
    return __builtin_amdgcn_fmed3f(v, -30.f, 30.f);
}

// d = hi * (sigmoid(S*(hi-b)) + sigmoid(-S*(hi+b)))
//   = hi * (2 + ea + eb) / ((1+ea)*(1+eb)),  ea=exp(-S*(hi-b)), eb=exp(S*(hi+b))
// clamp exp args to +-30 (fmed3) so ea*eb stays finite -> no inf*0 NaN.
__device__ __forceinline__ float sgate(float hi, float b) {
    const float ea = __expf(clamp30(-SLOPE * (hi - b)));
    const float eb = __expf(clamp30( SLOPE * (hi + b)));
    return hi * (2.f + ea + eb) * __builtin_amdgcn_rcpf((1.f + ea) * (1.f + eb));
}

__device__ __forceinline__ void nt_store4(float* p, float a, float b, float c, float d) {
    vfloat4 v = { a, b, c, d };
    __builtin_nontemporal_store(v, (vfloat4*)p);
}

__global__ __launch_bounds__(256) void lwpt_kernel(
    const float* __restrict__ x, const float* __restrict__ h_lo,
    const float* __restrict__ bias, float* __restrict__ out)
{
    __shared__ float bufA[2048];   // level-1 lo
    __shared__ float bufB[1024];   // level-2 lo

    const int bc  = blockIdx.x;          // row index (b*32 + c)
    const int c   = bc & (CHANS - 1);
    const int tid = threadIdx.x;

    const float* xrow = x   + (size_t)bc * TLEN;
    float*       orow = out + (size_t)bc * TLEN;

    // filters: h_lo is [C, LEVEL, 4] f32 -> one float4 per (c,l)
    const float4 k0v = ((const float4*)h_lo)[c * LEVELS + 0];
    const float4 k1v = ((const float4*)h_lo)[c * LEVELS + 1];
    const float b0 = bias[c * LEVELS + 0];
    const float b1 = bias[c * LEVELS + 1];

    // ---- Level 1: global -> lo in bufA[0..2048), d1 -> orow[2048..4096)
    {
        const float4* x4 = (const float4*)xrow;
        float in[18];
        #pragma unroll
        for (int k = 0; k < 4; ++k) {
            const float4 v = x4[4 * tid + k];
            in[4*k+0] = v.x; in[4*k+1] = v.y; in[4*k+2] = v.z; in[4*k+3] = v.w;
        }
        const float2 e = *(const float2*)(xrow + ((16 * tid + 16) & (TLEN - 1)));
        in[16] = e.x; in[17] = e.y;

        float lo[8], dd[8];
        #pragma unroll
        for (int j = 0; j < 8; ++j) {
            const float a0 = in[2*j], a1 = in[2*j+1], a2 = in[2*j+2], a3 = in[2*j+3];
            lo[j] = a0*k0v.x + a1*k0v.y + a2*k0v.z + a3*k0v.w;
            const float hi = a0*k0v.w - a1*k0v.z + a2*k0v.y - a3*k0v.x;
            dd[j] = sgate(hi, b0);
        }
        ((float4*)bufA)[2*tid]   = make_float4(lo[0], lo[1], lo[2], lo[3]);
        ((float4*)bufA)[2*tid+1] = make_float4(lo[4], lo[5], lo[6], lo[7]);
        nt_store4(orow + 2048 + 8*tid,     dd[0], dd[1], dd[2], dd[3]);
        nt_store4(orow + 2048 + 8*tid + 4, dd[4], dd[5], dd[6], dd[7]);
    }
    __syncthreads();

    // ---- Level 2: bufA[0..2048) -> lo in bufB[0..1024), d2 -> orow[1024..2048)
    {
        float in[10];
        #pragma unroll
        for (int k = 0; k < 2; ++k) {
            const float4 v = ((const float4*)bufA)[2 * tid + k];
            in[4*k+0] = v.x; in[4*k+1] = v.y; in[4*k+2] = v.z; in[4*k+3] = v.w;
        }
        const float2 e = *(const float2*)(bufA + ((8 * tid + 8) & 2047));
        in[8] = e.x; in[9] = e.y;

        float lo[4], dd[4];
        #pragma unroll
        for (int j = 0; j < 4; ++j) {
            const float a0 = in[2*j], a1 = in[2*j+1], a2 = in[2*j+2], a3 = in[2*j+3];
            lo[j] = a0*k1v.x + a1*k1v.y + a2*k1v.z + a3*k1v.w;
            const float hi = a0*k1v.w - a1*k1v.z + a2*k1v.y - a3*k1v.x;
            dd[j] = sgate(hi, b1);
        }
        ((float4*)bufB)[tid] = make_float4(lo[0], lo[1], lo[2], lo[3]);
        nt_store4(orow + 1024 + 4*tid, dd[0], dd[1], dd[2], dd[3]);
    }
    __syncthreads();

    // ---- Levels 3+4: wave 0 only, lo3/lo4 cascade in registers, halo via shuffle
    if (tid < 64) {
        const int lane = tid;
        const float4 k2v = ((const float4*)h_lo)[c * LEVELS + 2];
        const float4 k3v = ((const float4*)h_lo)[c * LEVELS + 3];
        const float b2 = bias[c * LEVELS + 2];
        const float b3 = bias[c * LEVELS + 3];

        // level 3: bufB (1024) -> lo3[8]/lane, d3 -> orow[512..1024)
        float in[18];
        #pragma unroll
        for (int k = 0; k < 4; ++k) {
            const float4 v = ((const float4*)bufB)[4 * lane + k];
            in[4*k+0] = v.x; in[4*k+1] = v.y; in[4*k+2] = v.z; in[4*k+3] = v.w;
        }
        const float2 e = *(const float2*)(bufB + ((16 * lane + 16) & 1023));
        in[16] = e.x; in[17] = e.y;

        float lo3[8], dd3[8];
        #pragma unroll
        for (int j = 0; j < 8; ++j) {
            const float a0 = in[2*j], a1 = in[2*j+1], a2 = in[2*j+2], a3 = in[2*j+3];
            lo3[j] = a0*k2v.x + a1*k2v.y + a2*k2v.z + a3*k2v.w;
            const float hi = a0*k2v.w - a1*k2v.z + a2*k2v.y - a3*k2v.x;
            dd3[j] = sgate(hi, b2);
        }
        nt_store4(orow + 512 + 8*lane,     dd3[0], dd3[1], dd3[2], dd3[3]);
        nt_store4(orow + 512 + 8*lane + 4, dd3[4], dd3[5], dd3[6], dd3[7]);

        // level 4: lo3[8]/lane (+2 halo from next lane, wraps at 63->0 = row wrap)
        const int nxt = (lane + 1) & 63;
        const float n0 = __shfl(lo3[0], nxt, 64);
        const float n1 = __shfl(lo3[1], nxt, 64);
        float lo4[4], dd4[4];
        #pragma unroll
        for (int j = 0; j < 4; ++j) {
            const float a0 = lo3[2*j];
            const float a1 = lo3[2*j+1];
            const float a2 = (2*j+2 < 8) ? lo3[2*j+2] : n0;
            const float a3 = (2*j+3 < 8) ? lo3[2*j+3] : n1;
            lo4[j] = a0*k3v.x + a1*k3v.y + a2*k3v.z + a3*k3v.w;
            const float hi = a0*k3v.w - a1*k3v.z + a2*k3v.y - a3*k3v.x;
            dd4[j] = sgate(hi, b3);
        }
        nt_store4(orow + 4*lane,       lo4[0], lo4[1], lo4[2], lo4[3]);
        nt_store4(orow + 256 + 4*lane, dd4[0], dd4[1], dd4[2], dd4[3]);
    }
}

extern "C" void kernel_launch(void* const* d_in, const int* in_sizes, int n_in,
                              void* d_out, int out_size, void* d_ws, size_t ws_size,
                              hipStream_t stream) {
    const float* x    = (const float*)d_in[0];
    const float* h_lo = (const float*)d_in[1];
    const float* bias = (const float*)d_in[2];
    float* out = (float*)d_out;

    dim3 grid(128 * CHANS);
    dim3 block(256);
    lwpt_kernel<<<grid, block, 0, stream>>>(x, h_lo, bias, out);
}

// Round 5
// 27.437 us; speedup vs baseline: 1.0501x; 1.0501x over previous
//
#include <hip/hip_runtime.h>
#include <math.h>

#define TLEN 4096
#define LEVELS 4
#define CHANS 32
#define SLOPE 10.0f

typedef float vfloat4 __attribute__((ext_vector_type(4)));
typedef float vfloat2 __attribute__((ext_vector_type(2)));

__device__ __forceinline__ float clamp30(float v) {
    return __builtin_amdgcn_fmed3f(v, -30.f, 30.f);
}

// d = hi * (sigmoid(S*(hi-b)) + sigmoid(-S*(hi+b)))
//   = hi * (2 + ea + eb) / ((1+ea)*(1+eb)),  ea=exp(-S*(hi-b)), eb=exp(S*(hi+b))
// clamp exp args to +-30 (fmed3) so ea*eb stays finite -> no inf*0 NaN.
__device__ __forceinline__ float sgate(float hi, float b) {
    const float ea = __expf(clamp30(-SLOPE * (hi - b)));
    const float eb = __expf(clamp30( SLOPE * (hi + b)));
    return hi * (2.f + ea + eb) * __builtin_amdgcn_rcpf((1.f + ea) * (1.f + eb));
}

__device__ __forceinline__ void nt_store4(float* p, float a, float b, float c, float d) {
    vfloat4 v = { a, b, c, d };
    __builtin_nontemporal_store(v, (vfloat4*)p);
}
__device__ __forceinline__ void nt_store2(float* p, float a, float b) {
    vfloat2 v = { a, b };
    __builtin_nontemporal_store(v, (vfloat2*)p);
}
__device__ __forceinline__ void nt_store1(float* p, float a) {
    __builtin_nontemporal_store(a, p);
}

__global__ __launch_bounds__(256) void lwpt_kernel(
    const float* __restrict__ x, const float* __restrict__ h_lo,
    const float* __restrict__ bias, float* __restrict__ out)
{
    __shared__ float bufA[2048];   // level-1 lo / level-3 lo (first 512)
    __shared__ float bufB[1024];   // level-2 lo

    const int bc  = blockIdx.x;          // row index (b*32 + c)
    const int c   = bc & (CHANS - 1);
    const int tid = threadIdx.x;

    const float* xrow = x   + (size_t)bc * TLEN;
    float*       orow = out + (size_t)bc * TLEN;

    // filters: h_lo is [C, LEVEL, 4] f32 -> one float4 per (c,l)
    const float4 k0v = ((const float4*)h_lo)[c * LEVELS + 0];
    const float4 k1v = ((const float4*)h_lo)[c * LEVELS + 1];
    const float4 k2v = ((const float4*)h_lo)[c * LEVELS + 2];
    const float4 k3v = ((const float4*)h_lo)[c * LEVELS + 3];
    const float b0 = bias[c * LEVELS + 0];
    const float b1 = bias[c * LEVELS + 1];
    const float b2 = bias[c * LEVELS + 2];
    const float b3 = bias[c * LEVELS + 3];

    // ---- Level 1: global -> lo in bufA[0..2048), d1 -> orow[2048..4096)
    {
        const float4* x4 = (const float4*)xrow;
        float in[18];
        #pragma unroll
        for (int k = 0; k < 4; ++k) {
            const float4 v = x4[4 * tid + k];
            in[4*k+0] = v.x; in[4*k+1] = v.y; in[4*k+2] = v.z; in[4*k+3] = v.w;
        }
        const float2 e = *(const float2*)(xrow + ((16 * tid + 16) & (TLEN - 1)));
        in[16] = e.x; in[17] = e.y;

        float lo[8], dd[8];
        #pragma unroll
        for (int j = 0; j < 8; ++j) {
            const float a0 = in[2*j], a1 = in[2*j+1], a2 = in[2*j+2], a3 = in[2*j+3];
            lo[j] = a0*k0v.x + a1*k0v.y + a2*k0v.z + a3*k0v.w;
            const float hi = a0*k0v.w - a1*k0v.z + a2*k0v.y - a3*k0v.x;
            dd[j] = sgate(hi, b0);
        }
        ((float4*)bufA)[2*tid]   = make_float4(lo[0], lo[1], lo[2], lo[3]);
        ((float4*)bufA)[2*tid+1] = make_float4(lo[4], lo[5], lo[6], lo[7]);
        nt_store4(orow + 2048 + 8*tid,     dd[0], dd[1], dd[2], dd[3]);
        nt_store4(orow + 2048 + 8*tid + 4, dd[4], dd[5], dd[6], dd[7]);
    }
    __syncthreads();

    // ---- Level 2: bufA[0..2048) -> lo in bufB[0..1024), d2 -> orow[1024..2048)
    {
        float in[10];
        #pragma unroll
        for (int k = 0; k < 2; ++k) {
            const float4 v = ((const float4*)bufA)[2 * tid + k];
            in[4*k+0] = v.x; in[4*k+1] = v.y; in[4*k+2] = v.z; in[4*k+3] = v.w;
        }
        const float2 e = *(const float2*)(bufA + ((8 * tid + 8) & 2047));
        in[8] = e.x; in[9] = e.y;

        float lo[4], dd[4];
        #pragma unroll
        for (int j = 0; j < 4; ++j) {
            const float a0 = in[2*j], a1 = in[2*j+1], a2 = in[2*j+2], a3 = in[2*j+3];
            lo[j] = a0*k1v.x + a1*k1v.y + a2*k1v.z + a3*k1v.w;
            const float hi = a0*k1v.w - a1*k1v.z + a2*k1v.y - a3*k1v.x;
            dd[j] = sgate(hi, b1);
        }
        ((float4*)bufB)[tid] = make_float4(lo[0], lo[1], lo[2], lo[3]);
        nt_store4(orow + 1024 + 4*tid, dd[0], dd[1], dd[2], dd[3]);
    }
    __syncthreads();

    // ---- Level 3: bufB[0..1024) -> lo in bufA[0..512), d3 -> orow[512..1024)
    {
        float in[6];
        const float4 v = ((const float4*)bufB)[tid];
        in[0] = v.x; in[1] = v.y; in[2] = v.z; in[3] = v.w;
        const float2 e = *(const float2*)(bufB + ((4 * tid + 4) & 1023));
        in[4] = e.x; in[5] = e.y;

        float lo[2], dd[2];
        #pragma unroll
        for (int j = 0; j < 2; ++j) {
            const float a0 = in[2*j], a1 = in[2*j+1], a2 = in[2*j+2], a3 = in[2*j+3];
            lo[j] = a0*k2v.x + a1*k2v.y + a2*k2v.z + a3*k2v.w;
            const float hi = a0*k2v.w - a1*k2v.z + a2*k2v.y - a3*k2v.x;
            dd[j] = sgate(hi, b2);
        }
        ((float2*)bufA)[tid] = make_float2(lo[0], lo[1]);
        nt_store2(orow + 512 + 2*tid, dd[0], dd[1]);
    }
    __syncthreads();

    // ---- Level 4: bufA[0..512) -> yl in orow[0..256), d4 -> orow[256..512)
    {
        const float2 a01 = *(const float2*)(bufA + 2 * tid);
        const float2 e   = *(const float2*)(bufA + ((2 * tid + 2) & 511));
        const float a0 = a01.x, a1 = a01.y, a2 = e.x, a3 = e.y;
        const float lo = a0*k3v.x + a1*k3v.y + a2*k3v.z + a3*k3v.w;
        const float hi = a0*k3v.w - a1*k3v.z + a2*k3v.y - a3*k3v.x;
        nt_store1(orow + tid,       lo);
        nt_store1(orow + 256 + tid, sgate(hi, b3));
    }
}

extern "C" void kernel_launch(void* const* d_in, const int* in_sizes, int n_in,
                              void* d_out, int out_size, void* d_ws, size_t ws_size,
                              hipStream_t stream) {
    const float* x    = (const float*)d_in[0];
    const float* h_lo = (const float*)d_in[1];
    const float* bias = (const float*)d_in[2];
    float* out = (float*)d_out;

    dim3 grid(128 * CHANS);
    dim3 block(256);
    lwpt_kernel<<<grid, block, 0, stream>>>(x, h_lo, bias, out);
}

// Round 6
// 26.287 us; speedup vs baseline: 1.0961x; 1.0437x over previous
//
#include <hip/hip_runtime.h>
#include <math.h>

#define TLEN 4096
#define LEVELS 4
#define CHANS 32
#define SLOPE 10.0f

__device__ __forceinline__ float clamp30(float v) {
    return __builtin_amdgcn_fmed3f(v, -30.f, 30.f);
}

// d = hi * (sigmoid(S*(hi-b)) + sigmoid(-S*(hi+b)))
//   = hi * (2 + ea + eb) / ((1+ea)*(1+eb)),  ea=exp(-S*(hi-b)), eb=exp(S*(hi+b))
// clamp exp args to +-30 (fmed3) so ea*eb stays finite -> no inf*0 NaN.
__device__ __forceinline__ float sgate(float hi, float b) {
    const float ea = __expf(clamp30(-SLOPE * (hi - b)));
    const float eb = __expf(clamp30( SLOPE * (hi + b)));
    return hi * (2.f + ea + eb) * __builtin_amdgcn_rcpf((1.f + ea) * (1.f + eb));
}

__global__ __launch_bounds__(256) void lwpt_kernel(
    const float* __restrict__ x, const float* __restrict__ h_lo,
    const float* __restrict__ bias, float* __restrict__ out)
{
    // bufA: level-1 lo, DE-INTERLEAVED: [0,1024) = per-lane lo[0..3] chunks,
    //       [1024,2048) = per-lane lo[4..7] chunks  (all LDS ops lane-contiguous)
    //       reused for level-3 lo (first 512).
    __shared__ float bufA[2048];
    __shared__ float bufB[1024];   // level-2 lo

    const int bc  = blockIdx.x;          // row index (b*32 + c)
    const int c   = bc & (CHANS - 1);
    const int tid = threadIdx.x;

    const float* xrow = x   + (size_t)bc * TLEN;
    float*       orow = out + (size_t)bc * TLEN;

    // filters: h_lo is [C, LEVEL, 4] f32 -> one float4 per (c,l)
    const float4 k0v = ((const float4*)h_lo)[c * LEVELS + 0];
    const float4 k1v = ((const float4*)h_lo)[c * LEVELS + 1];
    const float4 k2v = ((const float4*)h_lo)[c * LEVELS + 2];
    const float4 k3v = ((const float4*)h_lo)[c * LEVELS + 3];
    const float b0 = bias[c * LEVELS + 0];
    const float b1 = bias[c * LEVELS + 1];
    const float b2 = bias[c * LEVELS + 2];
    const float b3 = bias[c * LEVELS + 3];

    // ---- Level 1: global -> lo in bufA (split halves), d1 -> orow[2048..4096)
    {
        const float4* x4 = (const float4*)xrow;
        float in[18];
        #pragma unroll
        for (int k = 0; k < 4; ++k) {
            const float4 v = x4[4 * tid + k];
            in[4*k+0] = v.x; in[4*k+1] = v.y; in[4*k+2] = v.z; in[4*k+3] = v.w;
        }
        const float2 e = *(const float2*)(xrow + ((16 * tid + 16) & (TLEN - 1)));
        in[16] = e.x; in[17] = e.y;

        float lo[8], dd[8];
        #pragma unroll
        for (int j = 0; j < 8; ++j) {
            const float a0 = in[2*j], a1 = in[2*j+1], a2 = in[2*j+2], a3 = in[2*j+3];
            lo[j] = a0*k0v.x + a1*k0v.y + a2*k0v.z + a3*k0v.w;
            const float hi = a0*k0v.w - a1*k0v.z + a2*k0v.y - a3*k0v.x;
            dd[j] = sgate(hi, b0);
        }
        ((float4*)bufA)[tid]          = make_float4(lo[0], lo[1], lo[2], lo[3]);
        ((float4*)(bufA + 1024))[tid] = make_float4(lo[4], lo[5], lo[6], lo[7]);
        float4* o4 = (float4*)(orow + 2048);
        o4[2*tid]   = make_float4(dd[0], dd[1], dd[2], dd[3]);
        o4[2*tid+1] = make_float4(dd[4], dd[5], dd[6], dd[7]);
    }
    __syncthreads();

    // ---- Level 2: bufA (de-interleaved) -> lo in bufB, d2 -> orow[1024..2048)
    {
        float in[10];
        const float4 v0 = ((const float4*)bufA)[tid];          // out1[8t..8t+3]
        const float4 v1 = ((const float4*)(bufA + 1024))[tid]; // out1[8t+4..8t+7]
        in[0] = v0.x; in[1] = v0.y; in[2] = v0.z; in[3] = v0.w;
        in[4] = v1.x; in[5] = v1.y; in[6] = v1.z; in[7] = v1.w;
        const float2 e = *(const float2*)(bufA + ((4 * (tid + 1)) & 1023)); // out1[8t+8..9]
        in[8] = e.x; in[9] = e.y;

        float lo[4], dd[4];
        #pragma unroll
        for (int j = 0; j < 4; ++j) {
            const float a0 = in[2*j], a1 = in[2*j+1], a2 = in[2*j+2], a3 = in[2*j+3];
            lo[j] = a0*k1v.x + a1*k1v.y + a2*k1v.z + a3*k1v.w;
            const float hi = a0*k1v.w - a1*k1v.z + a2*k1v.y - a3*k1v.x;
            dd[j] = sgate(hi, b1);
        }
        ((float4*)bufB)[tid] = make_float4(lo[0], lo[1], lo[2], lo[3]);
        ((float4*)(orow + 1024))[tid] = make_float4(dd[0], dd[1], dd[2], dd[3]);
    }
    __syncthreads();

    // ---- Level 3: bufB[0..1024) -> lo in bufA[0..512), d3 -> orow[512..1024)
    {
        float in[6];
        const float4 v = ((const float4*)bufB)[tid];
        in[0] = v.x; in[1] = v.y; in[2] = v.z; in[3] = v.w;
        const float2 e = *(const float2*)(bufB + ((4 * tid + 4) & 1023));
        in[4] = e.x; in[5] = e.y;

        float lo[2], dd[2];
        #pragma unroll
        for (int j = 0; j < 2; ++j) {
            const float a0 = in[2*j], a1 = in[2*j+1], a2 = in[2*j+2], a3 = in[2*j+3];
            lo[j] = a0*k2v.x + a1*k2v.y + a2*k2v.z + a3*k2v.w;
            const float hi = a0*k2v.w - a1*k2v.z + a2*k2v.y - a3*k2v.x;
            dd[j] = sgate(hi, b2);
        }
        ((float2*)bufA)[tid] = make_float2(lo[0], lo[1]);
        ((float2*)(orow + 512))[tid] = make_float2(dd[0], dd[1]);
    }
    __syncthreads();

    // ---- Level 4: bufA[0..512) -> yl in orow[0..256), d4 -> orow[256..512)
    {
        const float2 a01 = *(const float2*)(bufA + 2 * tid);
        const float2 e   = *(const float2*)(bufA + ((2 * tid + 2) & 511));
        const float a0 = a01.x, a1 = a01.y, a2 = e.x, a3 = e.y;
        const float lo = a0*k3v.x + a1*k3v.y + a2*k3v.z + a3*k3v.w;
        const float hi = a0*k3v.w - a1*k3v.z + a2*k3v.y - a3*k3v.x;
        orow[tid]       = lo;
        orow[256 + tid] = sgate(hi, b3);
    }
}

extern "C" void kernel_launch(void* const* d_in, const int* in_sizes, int n_in,
                              void* d_out, int out_size, void* d_ws, size_t ws_size,
                              hipStream_t stream) {
    const float* x    = (const float*)d_in[0];
    const float* h_lo = (const float*)d_in[1];
    const float* bias = (const float*)d_in[2];
    float* out = (float*)d_out;

    dim3 grid(128 * CHANS);
    dim3 block(256);
    lwpt_kernel<<<grid, block, 0, stream>>>(x, h_lo, bias, out);
}